// Round 1
// baseline (1610.556 us; speedup 1.0000x reference)
//
#include <hip/hip_runtime.h>
#include <math.h>

#define D_MODEL 1024
#define D_FF    4096
#define NEXP    8
#define NTOK    8192
#define NASSIGN (NTOK*2)

using short8 = __attribute__((ext_vector_type(8))) short;
using f32x4  = __attribute__((ext_vector_type(4))) float;

__device__ __forceinline__ short f2bf(float f) {
  unsigned u = __float_as_uint(f);
  unsigned r = (u + 0x7fffu + ((u >> 16) & 1u)) >> 16;
  return (short)r;
}

__device__ __forceinline__ void gload_lds16(const void* g, void* l) {
  __builtin_amdgcn_global_load_lds((const __attribute__((address_space(1))) void*)g,
                                   (__attribute__((address_space(3))) void*)l, 16, 0, 0);
}

// ---------------- zero out + control ----------------
__global__ __launch_bounds__(256) void zero_kernel(float* out, int n_out, int* ctrl, float* psum) {
  int i = blockIdx.x * 256 + threadIdx.x;
  int stride = gridDim.x * 256;
  for (int j = i; j < n_out; j += stride) out[j] = 0.f;
  if (i < 24) ctrl[i] = 0;   // cnt[8], cursor[8], off[8]
  if (i < 8)  psum[i] = 0.f;
}

// ---------------- x fp32 -> bf16 ----------------
__global__ __launch_bounds__(256) void convert_x(const float4* __restrict__ x, ushort4* __restrict__ xb, int n4) {
  int i = blockIdx.x * 256 + threadIdx.x;
  if (i < n4) {
    float4 v = x[i];
    ushort4 o;
    o.x = (unsigned short)f2bf(v.x);
    o.y = (unsigned short)f2bf(v.y);
    o.z = (unsigned short)f2bf(v.z);
    o.w = (unsigned short)f2bf(v.w);
    xb[i] = o;
  }
}

// ---------------- transpose + convert: in[e][R][C] fp32 -> out[e][C][R] bf16 ----------------
__global__ __launch_bounds__(256) void transpose_conv(const float* __restrict__ in, short* __restrict__ out,
                                                      int R, int C) {
  __shared__ float t[64][65];
  int e = blockIdx.z;
  size_t base = (size_t)e * R * C;
  int r0 = blockIdx.y * 64, c0 = blockIdx.x * 64;
  int lr = threadIdx.x >> 6, lc = threadIdx.x & 63;
#pragma unroll
  for (int j = 0; j < 16; ++j) {
    int rr = lr + j * 4;
    t[rr][lc] = in[base + (size_t)(r0 + rr) * C + c0 + lc];
  }
  __syncthreads();
#pragma unroll
  for (int j = 0; j < 16; ++j) {
    int oc = lr + j * 4;  // output row within tile = input col
    out[base + (size_t)(c0 + oc) * R + r0 + lc] = f2bf(t[lc][oc]);
  }
}

// ---------------- gating: one wave per token ----------------
__global__ __launch_bounds__(256) void gating_kernel(const float* __restrict__ x, const float* __restrict__ Wg,
                                                     int* __restrict__ assign_e, float* __restrict__ assign_w,
                                                     int* __restrict__ cnt, float* __restrict__ psum) {
  int wv = threadIdx.x >> 6, lane = threadIdx.x & 63;
  int t = blockIdx.x * 4 + wv;
  const float* xr = x + (size_t)t * D_MODEL;
  float acc[NEXP];
#pragma unroll
  for (int e = 0; e < NEXP; ++e) acc[e] = 0.f;
#pragma unroll
  for (int i = 0; i < 16; ++i) {
    int row = lane + 64 * i;
    float xv = xr[row];
    const float* wr = Wg + row * NEXP;
#pragma unroll
    for (int e = 0; e < NEXP; ++e) acc[e] += xv * wr[e];
  }
#pragma unroll
  for (int off = 32; off; off >>= 1)
#pragma unroll
    for (int e = 0; e < NEXP; ++e) acc[e] += __shfl_down(acc[e], off);
  if (lane == 0) {
    float m = acc[0];
#pragma unroll
    for (int e = 1; e < NEXP; ++e) m = fmaxf(m, acc[e]);
    float p[NEXP], s = 0.f;
#pragma unroll
    for (int e = 0; e < NEXP; ++e) { p[e] = expf(acc[e] - m); s += p[e]; }
    float inv = 1.f / s;
#pragma unroll
    for (int e = 0; e < NEXP; ++e) p[e] *= inv;
    int i0 = 0; float v0 = p[0];
#pragma unroll
    for (int e = 1; e < NEXP; ++e) if (p[e] > v0) { v0 = p[e]; i0 = e; }
    int i1 = -1; float v1 = -1.f;
#pragma unroll
    for (int e = 0; e < NEXP; ++e) if (e != i0 && p[e] > v1) { v1 = p[e]; i1 = e; }
    float denom = 1.f / (v0 + v1 + 1e-9f);
    float w0 = v0 * denom, w1 = v1 * denom;
    assign_e[2 * t] = i0;     assign_w[2 * t] = w0;
    assign_e[2 * t + 1] = i1; assign_w[2 * t + 1] = w1;
    atomicAdd(&cnt[i0], 1);
    atomicAdd(&cnt[i1], 1);
#pragma unroll
    for (int e = 0; e < NEXP; ++e) atomicAdd(&psum[e], p[e]);
  }
}

// ---------------- scan: offsets + aux loss ----------------
__global__ void scan_kernel(const int* __restrict__ cnt, const float* __restrict__ psum,
                            int* __restrict__ offs, float* __restrict__ aux_out) {
  if (threadIdx.x == 0) {
    int o = 0; float aux = 0.f;
    for (int e = 0; e < NEXP; ++e) {
      offs[e] = o; o += cnt[e];
      aux += (float)cnt[e] * psum[e];
    }
    aux_out[0] = aux * (float)NEXP / ((float)NTOK * (float)NTOK);
  }
}

// ---------------- scatter: compact assignments per expert ----------------
__global__ __launch_bounds__(256) void scatter_kernel(const int* __restrict__ assign_e, const float* __restrict__ assign_w,
                                                      const int* __restrict__ offs, int* __restrict__ cursor,
                                                      int* __restrict__ slot_tok, float* __restrict__ slot_w) {
  int a = blockIdx.x * 256 + threadIdx.x;
  if (a < NASSIGN) {
    int e = assign_e[a];
    int pos = atomicAdd(&cursor[e], 1);
    int s = offs[e] + pos;
    slot_tok[s] = a >> 1;
    slot_w[s] = assign_w[a];
  }
}

// ---------------- GEMM1: H = gelu(gather(x) @ W1[e] + b1[e]) -> bf16 ----------------
__global__ __launch_bounds__(256) void gemm1_kernel(const short* __restrict__ xb, const short* __restrict__ w1t,
                                                    const float* __restrict__ b1, const int* __restrict__ slot_tok,
                                                    const int* __restrict__ cnt, const int* __restrict__ offs,
                                                    short* __restrict__ H) {
  int e = blockIdx.z;
  int cn = cnt[e];
  int rt = blockIdx.y;
  if (rt * 128 >= cn) return;
  int ft = blockIdx.x;
  int off = offs[e];

  __shared__ short As[128 * 32];
  __shared__ short Bs[128 * 32];
  __shared__ int s_tok[128];

  int tid = threadIdx.x;
  if (tid < 128) {
    int grow = rt * 128 + tid;
    int idx = grow < cn ? grow : cn - 1;
    s_tok[tid] = slot_tok[off + idx];
  }
  int lane = tid & 63, wv = tid >> 6;
  int wr = wv >> 1, wc = wv & 1;
  int l15 = lane & 15, kh = lane >> 4;
  f32x4 acc[4][4] = {};

  const short* w1e = w1t + (size_t)e * D_FF * D_MODEL + (size_t)(ft * 128) * D_MODEL;
  int srow = tid >> 2, sc8 = (tid & 3) * 8;

  for (int k0 = 0; k0 < D_MODEL; k0 += 32) {
    __syncthreads();
    gload_lds16(xb + (size_t)s_tok[srow] * D_MODEL + k0 + sc8,        (char*)As + tid * 16);
    gload_lds16(xb + (size_t)s_tok[srow + 64] * D_MODEL + k0 + sc8,   (char*)As + 4096 + tid * 16);
    gload_lds16(w1e + (size_t)srow * D_MODEL + k0 + sc8,              (char*)Bs + tid * 16);
    gload_lds16(w1e + (size_t)(srow + 64) * D_MODEL + k0 + sc8,       (char*)Bs + 4096 + tid * 16);
    __syncthreads();
    const short* Ab = As + (wr * 64 + l15) * 32 + kh * 8;
    const short* Bb = Bs + (wc * 64 + l15) * 32 + kh * 8;
    short8 af[4], bq[4];
#pragma unroll
    for (int m = 0; m < 4; ++m) af[m] = *(const short8*)(Ab + m * 512);
#pragma unroll
    for (int n = 0; n < 4; ++n) bq[n] = *(const short8*)(Bb + n * 512);
#pragma unroll
    for (int m = 0; m < 4; ++m)
#pragma unroll
      for (int n = 0; n < 4; ++n)
        acc[m][n] = __builtin_amdgcn_mfma_f32_16x16x32_bf16(af[m], bq[n], acc[m][n], 0, 0, 0);
  }

#pragma unroll
  for (int m = 0; m < 4; ++m) {
    int rbase = wr * 64 + m * 16 + kh * 4;
#pragma unroll
    for (int n = 0; n < 4; ++n) {
      int col = ft * 128 + wc * 64 + n * 16 + l15;
      float bias = b1[e * D_FF + col];
#pragma unroll
      for (int j = 0; j < 4; ++j) {
        int grow = rt * 128 + rbase + j;
        if (grow < cn) {
          float v = acc[m][n][j] + bias;
          v = 0.5f * v * (1.f + erff(v * 0.70710678118f));  // exact gelu
          H[(size_t)(off + grow) * D_FF + col] = f2bf(v);
        }
      }
    }
  }
}

// ---------------- GEMM2: out[tok] += w * (H @ W2[e] + b2[e]) ----------------
__global__ __launch_bounds__(256) void gemm2_kernel(const short* __restrict__ H, const short* __restrict__ w2t,
                                                    const float* __restrict__ b2, const int* __restrict__ slot_tok,
                                                    const float* __restrict__ slot_w, const int* __restrict__ cnt,
                                                    const int* __restrict__ offs, float* __restrict__ out) {
  int e = blockIdx.z;
  int cn = cnt[e];
  int rt = blockIdx.y;
  if (rt * 128 >= cn) return;
  int dt = blockIdx.x;
  int off = offs[e];

  __shared__ short As[128 * 32];
  __shared__ short Bs[128 * 32];

  int tid = threadIdx.x, lane = tid & 63, wv = tid >> 6;
  int wr = wv >> 1, wc = wv & 1;
  int l15 = lane & 15, kh = lane >> 4;
  f32x4 acc[4][4] = {};

  const short* w2e = w2t + (size_t)e * D_MODEL * D_FF + (size_t)(dt * 128) * D_FF;
  const short* Hb = H + (size_t)off * D_FF;
  int srow = tid >> 2, sc8 = (tid & 3) * 8;
  int g0 = rt * 128 + srow, g1 = rt * 128 + srow + 64;
  int ar0 = g0 < cn ? g0 : cn - 1;
  int ar1 = g1 < cn ? g1 : cn - 1;

  for (int k0 = 0; k0 < D_FF; k0 += 32) {
    __syncthreads();
    gload_lds16(Hb + (size_t)ar0 * D_FF + k0 + sc8,             (char*)As + tid * 16);
    gload_lds16(Hb + (size_t)ar1 * D_FF + k0 + sc8,             (char*)As + 4096 + tid * 16);
    gload_lds16(w2e + (size_t)srow * D_FF + k0 + sc8,           (char*)Bs + tid * 16);
    gload_lds16(w2e + (size_t)(srow + 64) * D_FF + k0 + sc8,    (char*)Bs + 4096 + tid * 16);
    __syncthreads();
    const short* Ab = As + (wr * 64 + l15) * 32 + kh * 8;
    const short* Bb = Bs + (wc * 64 + l15) * 32 + kh * 8;
    short8 af[4], bq[4];
#pragma unroll
    for (int m = 0; m < 4; ++m) af[m] = *(const short8*)(Ab + m * 512);
#pragma unroll
    for (int n = 0; n < 4; ++n) bq[n] = *(const short8*)(Bb + n * 512);
#pragma unroll
    for (int m = 0; m < 4; ++m)
#pragma unroll
      for (int n = 0; n < 4; ++n)
        acc[m][n] = __builtin_amdgcn_mfma_f32_16x16x32_bf16(af[m], bq[n], acc[m][n], 0, 0, 0);
  }

#pragma unroll
  for (int m = 0; m < 4; ++m) {
    int rbase = wr * 64 + m * 16 + kh * 4;
#pragma unroll
    for (int n = 0; n < 4; ++n) {
      int col = dt * 128 + wc * 64 + n * 16 + l15;
      float bias = b2[e * D_MODEL + col];
#pragma unroll
      for (int j = 0; j < 4; ++j) {
        int grow = rt * 128 + rbase + j;
        if (grow < cn) {
          int s = off + grow;
          float v = slot_w[s] * (acc[m][n][j] + bias);
          atomicAdd(&out[(size_t)slot_tok[s] * D_MODEL + col], v);
        }
      }
    }
  }
}

extern "C" void kernel_launch(void* const* d_in, const int* in_sizes, int n_in,
                              void* d_out, int out_size, void* d_ws, size_t ws_size,
                              hipStream_t stream) {
  const float* x  = (const float*)d_in[0];
  const float* Wg = (const float*)d_in[1];
  const float* W1 = (const float*)d_in[2];
  const float* b1 = (const float*)d_in[3];
  const float* W2 = (const float*)d_in[4];
  const float* b2 = (const float*)d_in[5];
  float* out = (float*)d_out;
  char* ws = (char*)d_ws;

  // workspace layout (~285.5 MB)
  short* xb       = (short*)(ws);                       // 8192*1024 bf16        16,777,216 B
  short* w1t      = (short*)(ws + 16777216);            // [e][f][k] bf16        67,108,864 B
  short* w2t      = (short*)(ws + 83886080);            // [e][d][ff] bf16       67,108,864 B
  short* H        = (short*)(ws + 150994944);           // 16384 x 4096 bf16    134,217,728 B
  int*   slot_tok = (int*)  (ws + 285212672);           // 16384 int
  float* slot_w   = (float*)(ws + 285278208);           // 16384 float
  int*   assign_e = (int*)  (ws + 285343744);           // 16384 int
  float* assign_w = (float*)(ws + 285409280);           // 16384 float
  int*   ctrl     = (int*)  (ws + 285474816);           // cnt[8], cursor[8], off[8]
  float* psum     = (float*)(ws + 285474816 + 96);      // probs sum[8]
  int* cnt = ctrl; int* cursor = ctrl + 8; int* offs = ctrl + 16;

  zero_kernel<<<4096, 256, 0, stream>>>(out, out_size, ctrl, psum);
  convert_x<<<8192, 256, 0, stream>>>((const float4*)x, (ushort4*)xb, NTOK * D_MODEL / 4);
  transpose_conv<<<dim3(64, 16, NEXP), 256, 0, stream>>>(W1, w1t, D_MODEL, D_FF);
  transpose_conv<<<dim3(16, 64, NEXP), 256, 0, stream>>>(W2, w2t, D_FF, D_MODEL);
  gating_kernel<<<NTOK / 4, 256, 0, stream>>>(x, Wg, assign_e, assign_w, cnt, psum);
  scan_kernel<<<1, 64, 0, stream>>>(cnt, psum, offs, out + (out_size - 1));
  scatter_kernel<<<NASSIGN / 256, 256, 0, stream>>>(assign_e, assign_w, offs, cursor, slot_tok, slot_w);
  gemm1_kernel<<<dim3(D_FF / 128, 128, NEXP), 256, 0, stream>>>(xb, w1t, b1, slot_tok, cnt, offs, H);
  gemm2_kernel<<<dim3(D_MODEL / 128, 128, NEXP), 256, 0, stream>>>(H, w2t, b2, slot_tok, slot_w, cnt, offs, out);
}

// Round 2
// 678.725 us; speedup vs baseline: 2.3729x; 2.3729x over previous
//
#include <hip/hip_runtime.h>
#include <math.h>

#define D_MODEL 1024
#define D_FF    4096
#define NEXP    8
#define NTOK    8192
#define NASSIGN (NTOK*2)
#define NGBLK   (NTOK/4)   // gating blocks (4 tokens/block)

using short8 = __attribute__((ext_vector_type(8))) short;
using f32x4  = __attribute__((ext_vector_type(4))) float;

__device__ __forceinline__ short f2bf(float f) {
  unsigned u = __float_as_uint(f);
  unsigned r = (u + 0x7fffu + ((u >> 16) & 1u)) >> 16;
  return (short)r;
}

__device__ __forceinline__ void gload_lds16(const void* g, void* l) {
  __builtin_amdgcn_global_load_lds((const __attribute__((address_space(1))) void*)g,
                                   (__attribute__((address_space(3))) void*)l, 16, 0, 0);
}

// ---------------- zero control ----------------
__global__ void zero_kernel(int* ctrl) {
  int i = threadIdx.x;
  if (i < 24) ctrl[i] = 0;   // cnt[8], cursor[8], off[8]
}

// ---------------- x fp32 -> bf16 ----------------
__global__ __launch_bounds__(256) void convert_x(const float4* __restrict__ x, ushort4* __restrict__ xb, int n4) {
  int i = blockIdx.x * 256 + threadIdx.x;
  if (i < n4) {
    float4 v = x[i];
    ushort4 o;
    o.x = (unsigned short)f2bf(v.x);
    o.y = (unsigned short)f2bf(v.y);
    o.z = (unsigned short)f2bf(v.z);
    o.w = (unsigned short)f2bf(v.w);
    xb[i] = o;
  }
}

// ---------------- transpose + convert: in[e][R][C] fp32 -> out[e][C][R] bf16 ----------------
__global__ __launch_bounds__(256) void transpose_conv(const float* __restrict__ in, short* __restrict__ out,
                                                      int R, int C) {
  __shared__ float t[64][65];
  int e = blockIdx.z;
  size_t base = (size_t)e * R * C;
  int r0 = blockIdx.y * 64, c0 = blockIdx.x * 64;
  int lr = threadIdx.x >> 6, lc = threadIdx.x & 63;
#pragma unroll
  for (int j = 0; j < 16; ++j) {
    int rr = lr + j * 4;
    t[rr][lc] = in[base + (size_t)(r0 + rr) * C + c0 + lc];
  }
  __syncthreads();
#pragma unroll
  for (int j = 0; j < 16; ++j) {
    int oc = lr + j * 4;  // output row within tile = input col
    out[base + (size_t)(c0 + oc) * R + r0 + lc] = f2bf(t[lc][oc]);
  }
}

// ---------------- gating: one wave per token, block-local reduction ----------------
__global__ __launch_bounds__(256) void gating_kernel(const float* __restrict__ x, const float* __restrict__ Wg,
                                                     int* __restrict__ assign_e, float* __restrict__ assign_w,
                                                     int* __restrict__ cnt_part, float* __restrict__ psum_part) {
  __shared__ float l_ps[NEXP];
  __shared__ int   l_cnt[NEXP];
  int tid = threadIdx.x, wv = tid >> 6, lane = tid & 63;
  if (tid < NEXP) { l_ps[tid] = 0.f; l_cnt[tid] = 0; }
  __syncthreads();

  int t = blockIdx.x * 4 + wv;
  const float4* xr = (const float4*)(x + (size_t)t * D_MODEL);
  float acc[NEXP];
#pragma unroll
  for (int e = 0; e < NEXP; ++e) acc[e] = 0.f;
#pragma unroll
  for (int i = 0; i < 4; ++i) {
    int c4 = lane + 64 * i;
    float4 v = xr[c4];
    const float* wr = Wg + c4 * 4 * NEXP;
#pragma unroll
    for (int j = 0; j < 4; ++j) {
      float xv = (&v.x)[j];
#pragma unroll
      for (int e = 0; e < NEXP; ++e) acc[e] += xv * wr[j * NEXP + e];
    }
  }
#pragma unroll
  for (int off = 32; off; off >>= 1)
#pragma unroll
    for (int e = 0; e < NEXP; ++e) acc[e] += __shfl_down(acc[e], off);

  if (lane == 0) {
    float m = acc[0];
#pragma unroll
    for (int e = 1; e < NEXP; ++e) m = fmaxf(m, acc[e]);
    float p[NEXP], s = 0.f;
#pragma unroll
    for (int e = 0; e < NEXP; ++e) { p[e] = expf(acc[e] - m); s += p[e]; }
    float inv = 1.f / s;
#pragma unroll
    for (int e = 0; e < NEXP; ++e) p[e] *= inv;
    int i0 = 0; float v0 = p[0];
#pragma unroll
    for (int e = 1; e < NEXP; ++e) if (p[e] > v0) { v0 = p[e]; i0 = e; }
    int i1 = -1; float v1 = -1.f;
#pragma unroll
    for (int e = 0; e < NEXP; ++e) if (e != i0 && p[e] > v1) { v1 = p[e]; i1 = e; }
    float denom = 1.f / (v0 + v1 + 1e-9f);
    assign_e[2 * t] = i0;     assign_w[2 * t] = v0 * denom;
    assign_e[2 * t + 1] = i1; assign_w[2 * t + 1] = v1 * denom;
    atomicAdd(&l_cnt[i0], 1);
    atomicAdd(&l_cnt[i1], 1);
#pragma unroll
    for (int e = 0; e < NEXP; ++e) atomicAdd(&l_ps[e], p[e]);
  }
  __syncthreads();
  if (tid < NEXP) {
    psum_part[blockIdx.x * NEXP + tid] = l_ps[tid];
    cnt_part[blockIdx.x * NEXP + tid] = l_cnt[tid];
  }
}

// ---------------- scan: reduce partials -> cnt/offs + aux loss ----------------
__global__ __launch_bounds__(256) void scan_kernel(const int* __restrict__ cnt_part, const float* __restrict__ psum_part,
                                                   int* __restrict__ cnt, int* __restrict__ offs,
                                                   float* __restrict__ aux_out) {
  __shared__ float sp[256];
  __shared__ int   sc[256];
  int tid = threadIdx.x;
  int e = tid & 7, c = tid >> 3;          // 32 chunks per expert
  float fs = 0.f; int is = 0;
  for (int b = c; b < NGBLK; b += 32) {
    fs += psum_part[b * NEXP + e];
    is += cnt_part[b * NEXP + e];
  }
  sp[tid] = fs; sc[tid] = is;
  __syncthreads();
  if (tid < NEXP) {
    float f = 0.f; int n = 0;
    for (int c2 = 0; c2 < 32; ++c2) { f += sp[c2 * 8 + tid]; n += sc[c2 * 8 + tid]; }
    cnt[tid] = n; sp[tid] = f;            // stash psum total
  }
  __syncthreads();
  if (tid == 0) {
    int o = 0; float aux = 0.f;
    for (int e2 = 0; e2 < NEXP; ++e2) {
      offs[e2] = o; o += cnt[e2];
      aux += (float)cnt[e2] * sp[e2];
    }
    aux_out[0] = aux * (float)NEXP / ((float)NTOK * (float)NTOK);
  }
}

// ---------------- scatter: compact assignments per expert (block-aggregated atomics) ----------------
__global__ __launch_bounds__(256) void scatter_kernel(const int* __restrict__ assign_e,
                                                      const int* __restrict__ offs, int* __restrict__ cursor,
                                                      int* __restrict__ slot_tok, int* __restrict__ slot_of) {
  __shared__ int lhist[NEXP], lbase[NEXP];
  int tid = threadIdx.x;
  int a = blockIdx.x * 256 + tid;
  if (tid < NEXP) lhist[tid] = 0;
  __syncthreads();
  int e = assign_e[a];
  int lp = atomicAdd(&lhist[e], 1);
  __syncthreads();
  if (tid < NEXP) lbase[tid] = atomicAdd(&cursor[tid], lhist[tid]);
  __syncthreads();
  int s = offs[e] + lbase[e] + lp;
  slot_tok[s] = a >> 1;
  slot_of[a] = s;
}

// ---------------- GEMM1: H = gelu(gather(x) @ W1[e] + b1[e]) -> bf16 ----------------
__global__ __launch_bounds__(256) void gemm1_kernel(const short* __restrict__ xb, const short* __restrict__ w1t,
                                                    const float* __restrict__ b1, const int* __restrict__ slot_tok,
                                                    const int* __restrict__ cnt, const int* __restrict__ offs,
                                                    short* __restrict__ H) {
  int e = blockIdx.z;
  int cn = cnt[e];
  int rt = blockIdx.y;
  if (rt * 128 >= cn) return;
  int ft = blockIdx.x;
  int off = offs[e];

  __shared__ short As[128 * 32];
  __shared__ short Bs[128 * 32];
  __shared__ int s_tok[128];

  int tid = threadIdx.x;
  if (tid < 128) {
    int grow = rt * 128 + tid;
    int idx = grow < cn ? grow : cn - 1;
    s_tok[tid] = slot_tok[off + idx];
  }
  int lane = tid & 63, wv = tid >> 6;
  int wr = wv >> 1, wc = wv & 1;
  int l15 = lane & 15, kh = lane >> 4;
  f32x4 acc[4][4] = {};

  const short* w1e = w1t + (size_t)e * D_FF * D_MODEL + (size_t)(ft * 128) * D_MODEL;
  int srow = tid >> 2, sc8 = (tid & 3) * 8;

  for (int k0 = 0; k0 < D_MODEL; k0 += 32) {
    __syncthreads();
    gload_lds16(xb + (size_t)s_tok[srow] * D_MODEL + k0 + sc8,        (char*)As + tid * 16);
    gload_lds16(xb + (size_t)s_tok[srow + 64] * D_MODEL + k0 + sc8,   (char*)As + 4096 + tid * 16);
    gload_lds16(w1e + (size_t)srow * D_MODEL + k0 + sc8,              (char*)Bs + tid * 16);
    gload_lds16(w1e + (size_t)(srow + 64) * D_MODEL + k0 + sc8,       (char*)Bs + 4096 + tid * 16);
    __syncthreads();
    const short* Ab = As + (wr * 64 + l15) * 32 + kh * 8;
    const short* Bb = Bs + (wc * 64 + l15) * 32 + kh * 8;
    short8 af[4], bq[4];
#pragma unroll
    for (int m = 0; m < 4; ++m) af[m] = *(const short8*)(Ab + m * 512);
#pragma unroll
    for (int n = 0; n < 4; ++n) bq[n] = *(const short8*)(Bb + n * 512);
#pragma unroll
    for (int m = 0; m < 4; ++m)
#pragma unroll
      for (int n = 0; n < 4; ++n)
        acc[m][n] = __builtin_amdgcn_mfma_f32_16x16x32_bf16(af[m], bq[n], acc[m][n], 0, 0, 0);
  }

#pragma unroll
  for (int m = 0; m < 4; ++m) {
    int rbase = wr * 64 + m * 16 + kh * 4;
#pragma unroll
    for (int n = 0; n < 4; ++n) {
      int col = ft * 128 + wc * 64 + n * 16 + l15;
      float bias = b1[e * D_FF + col];
#pragma unroll
      for (int j = 0; j < 4; ++j) {
        int grow = rt * 128 + rbase + j;
        if (grow < cn) {
          float v = acc[m][n][j] + bias;
          v = 0.5f * v * (1.f + erff(v * 0.70710678118f));  // exact gelu
          H[(size_t)(off + grow) * D_FF + col] = f2bf(v);
        }
      }
    }
  }
}

// ---------------- GEMM2: y[slot] = H @ W2[e] + b2[e] (fp32, no atomics) ----------------
__global__ __launch_bounds__(256) void gemm2_kernel(const short* __restrict__ H, const short* __restrict__ w2t,
                                                    const float* __restrict__ b2,
                                                    const int* __restrict__ cnt, const int* __restrict__ offs,
                                                    float* __restrict__ y) {
  int e = blockIdx.z;
  int cn = cnt[e];
  int rt = blockIdx.y;
  if (rt * 128 >= cn) return;
  int dt = blockIdx.x;
  int off = offs[e];

  __shared__ short As[128 * 32];
  __shared__ short Bs[128 * 32];

  int tid = threadIdx.x, lane = tid & 63, wv = tid >> 6;
  int wr = wv >> 1, wc = wv & 1;
  int l15 = lane & 15, kh = lane >> 4;
  f32x4 acc[4][4] = {};

  const short* w2e = w2t + (size_t)e * D_MODEL * D_FF + (size_t)(dt * 128) * D_FF;
  const short* Hb = H + (size_t)off * D_FF;
  int srow = tid >> 2, sc8 = (tid & 3) * 8;
  int g0 = rt * 128 + srow, g1 = rt * 128 + srow + 64;
  int ar0 = g0 < cn ? g0 : cn - 1;
  int ar1 = g1 < cn ? g1 : cn - 1;

  for (int k0 = 0; k0 < D_FF; k0 += 32) {
    __syncthreads();
    gload_lds16(Hb + (size_t)ar0 * D_FF + k0 + sc8,             (char*)As + tid * 16);
    gload_lds16(Hb + (size_t)ar1 * D_FF + k0 + sc8,             (char*)As + 4096 + tid * 16);
    gload_lds16(w2e + (size_t)srow * D_FF + k0 + sc8,           (char*)Bs + tid * 16);
    gload_lds16(w2e + (size_t)(srow + 64) * D_FF + k0 + sc8,    (char*)Bs + 4096 + tid * 16);
    __syncthreads();
    const short* Ab = As + (wr * 64 + l15) * 32 + kh * 8;
    const short* Bb = Bs + (wc * 64 + l15) * 32 + kh * 8;
    short8 af[4], bq[4];
#pragma unroll
    for (int m = 0; m < 4; ++m) af[m] = *(const short8*)(Ab + m * 512);
#pragma unroll
    for (int n = 0; n < 4; ++n) bq[n] = *(const short8*)(Bb + n * 512);
#pragma unroll
    for (int m = 0; m < 4; ++m)
#pragma unroll
      for (int n = 0; n < 4; ++n)
        acc[m][n] = __builtin_amdgcn_mfma_f32_16x16x32_bf16(af[m], bq[n], acc[m][n], 0, 0, 0);
  }

#pragma unroll
  for (int m = 0; m < 4; ++m) {
    int rbase = wr * 64 + m * 16 + kh * 4;
#pragma unroll
    for (int n = 0; n < 4; ++n) {
      int col = dt * 128 + wc * 64 + n * 16 + l15;
      float bias = b2[e * D_MODEL + col];
#pragma unroll
      for (int j = 0; j < 4; ++j) {
        int grow = rt * 128 + rbase + j;
        if (grow < cn)
          y[(size_t)(off + grow) * D_MODEL + col] = acc[m][n][j] + bias;
      }
    }
  }
}

// ---------------- combine: out[t] = w0*y[s0] + w1*y[s1] ----------------
__global__ __launch_bounds__(256) void combine_kernel(const float* __restrict__ y, const int* __restrict__ slot_of,
                                                      const float* __restrict__ assign_w, float* __restrict__ out) {
  int t = blockIdx.x;
  int d4 = threadIdx.x;
  int s0 = slot_of[2 * t], s1 = slot_of[2 * t + 1];
  float w0 = assign_w[2 * t], w1 = assign_w[2 * t + 1];
  float4 a = ((const float4*)(y + (size_t)s0 * D_MODEL))[d4];
  float4 b = ((const float4*)(y + (size_t)s1 * D_MODEL))[d4];
  float4 o;
  o.x = w0 * a.x + w1 * b.x;
  o.y = w0 * a.y + w1 * b.y;
  o.z = w0 * a.z + w1 * b.z;
  o.w = w0 * a.w + w1 * b.w;
  ((float4*)(out + (size_t)t * D_MODEL))[d4] = o;
}

extern "C" void kernel_launch(void* const* d_in, const int* in_sizes, int n_in,
                              void* d_out, int out_size, void* d_ws, size_t ws_size,
                              hipStream_t stream) {
  const float* x  = (const float*)d_in[0];
  const float* Wg = (const float*)d_in[1];
  const float* W1 = (const float*)d_in[2];
  const float* b1 = (const float*)d_in[3];
  const float* W2 = (const float*)d_in[4];
  const float* b2 = (const float*)d_in[5];
  float* out = (float*)d_out;
  char* ws = (char*)d_ws;

  // workspace layout (~285.6 MB)
  short* xb       = (short*)(ws);                       // 16,777,216 B
  short* w1t      = (short*)(ws + 16777216);            // 67,108,864 B  [e][f][k] bf16
  float* y        = (float*)(ws + 16777216);            // aliases w1t (dead after gemm1): 16384x1024 fp32
  short* w2t      = (short*)(ws + 83886080);            // 67,108,864 B  [e][d][ff] bf16
  short* H        = (short*)(ws + 150994944);           // 134,217,728 B 16384 x 4096 bf16
  int*   slot_tok = (int*)  (ws + 285212672);           // 65,536 B
  int*   assign_e = (int*)  (ws + 285278208);           // 65,536 B
  float* assign_w = (float*)(ws + 285343744);           // 65,536 B
  int*   slot_of  = (int*)  (ws + 285409280);           // 65,536 B
  int*   cnt_part = (int*)  (ws + 285474816);           // 65,536 B
  float* psum_part= (float*)(ws + 285540352);           // 65,536 B
  int*   ctrl     = (int*)  (ws + 285605888);           // 96 B
  int* cnt = ctrl; int* cursor = ctrl + 8; int* offs = ctrl + 16;

  zero_kernel<<<1, 64, 0, stream>>>(ctrl);
  convert_x<<<8192, 256, 0, stream>>>((const float4*)x, (ushort4*)xb, NTOK * D_MODEL / 4);
  transpose_conv<<<dim3(64, 16, NEXP), 256, 0, stream>>>(W1, w1t, D_MODEL, D_FF);
  transpose_conv<<<dim3(16, 64, NEXP), 256, 0, stream>>>(W2, w2t, D_FF, D_MODEL);
  gating_kernel<<<NGBLK, 256, 0, stream>>>(x, Wg, assign_e, assign_w, cnt_part, psum_part);
  scan_kernel<<<1, 256, 0, stream>>>(cnt_part, psum_part, cnt, offs, out + (out_size - 1));
  scatter_kernel<<<NASSIGN / 256, 256, 0, stream>>>(assign_e, offs, cursor, slot_tok, slot_of);
  gemm1_kernel<<<dim3(D_FF / 128, 128, NEXP), 256, 0, stream>>>(xb, w1t, b1, slot_tok, cnt, offs, H);
  gemm2_kernel<<<dim3(D_MODEL / 128, 128, NEXP), 256, 0, stream>>>(H, w2t, b2, cnt, offs, y);
  combine_kernel<<<NTOK, 256, 0, stream>>>(y, slot_of, assign_w, out);
}

// Round 3
// 671.519 us; speedup vs baseline: 2.3984x; 1.0107x over previous
//
#include <hip/hip_runtime.h>
#include <math.h>

#define D_MODEL 1024
#define D_FF    4096
#define NEXP    8
#define NTOK    8192
#define NASSIGN (NTOK*2)
#define NGBLK   (NTOK/4)   // gating blocks (4 tokens/block)

using short8 = __attribute__((ext_vector_type(8))) short;
using f32x4  = __attribute__((ext_vector_type(4))) float;

__device__ __forceinline__ short f2bf(float f) {
  unsigned u = __float_as_uint(f);
  unsigned r = (u + 0x7fffu + ((u >> 16) & 1u)) >> 16;
  return (short)r;
}

__device__ __forceinline__ void gload_lds16(const void* g, void* l) {
  __builtin_amdgcn_global_load_lds((const __attribute__((address_space(1))) void*)g,
                                   (__attribute__((address_space(3))) void*)l, 16, 0, 0);
}

// fast erf-gelu: Abramowitz-Stegun 7.1.26, |eps| <= 1.5e-7
__device__ __forceinline__ float gelu_f(float x) {
  float z = 0.70710678118f * x;
  float a = fabsf(z);
  float t = 1.0f / (1.0f + 0.3275911f * a);
  float p = t * (0.254829592f + t * (-0.284496736f + t * (1.421413741f +
            t * (-1.453152027f + t * 1.061405429f))));
  float er = 1.0f - p * __expf(-a * a);
  er = copysignf(er, z);
  return 0.5f * x * (1.0f + er);
}

// ---------------- zero control ----------------
__global__ void zero_kernel(int* ctrl) {
  int i = threadIdx.x;
  if (i < 24) ctrl[i] = 0;   // cnt[8], cursor[8], off[8]
}

// ---------------- x fp32 -> bf16 ----------------
__global__ __launch_bounds__(256) void convert_x(const float4* __restrict__ x, ushort4* __restrict__ xb, int n4) {
  int i = blockIdx.x * 256 + threadIdx.x;
  if (i < n4) {
    float4 v = x[i];
    ushort4 o;
    o.x = (unsigned short)f2bf(v.x);
    o.y = (unsigned short)f2bf(v.y);
    o.z = (unsigned short)f2bf(v.z);
    o.w = (unsigned short)f2bf(v.w);
    xb[i] = o;
  }
}

// ---------------- transpose + convert: in[e][R][C] fp32 -> out[e][C][R] bf16 ----------------
__global__ __launch_bounds__(256) void transpose_conv(const float* __restrict__ in, short* __restrict__ out,
                                                      int R, int C) {
  __shared__ float t[64][65];
  int e = blockIdx.z;
  size_t base = (size_t)e * R * C;
  int r0 = blockIdx.y * 64, c0 = blockIdx.x * 64;
  int lr = threadIdx.x >> 6, lc = threadIdx.x & 63;
#pragma unroll
  for (int j = 0; j < 16; ++j) {
    int rr = lr + j * 4;
    t[rr][lc] = in[base + (size_t)(r0 + rr) * C + c0 + lc];
  }
  __syncthreads();
#pragma unroll
  for (int j = 0; j < 16; ++j) {
    int oc = lr + j * 4;
    out[base + (size_t)(c0 + oc) * R + r0 + lc] = f2bf(t[lc][oc]);
  }
}

// ---------------- gating: one wave per token, block-local reduction ----------------
__global__ __launch_bounds__(256) void gating_kernel(const float* __restrict__ x, const float* __restrict__ Wg,
                                                     int* __restrict__ assign_e, float* __restrict__ assign_w,
                                                     int* __restrict__ cnt_part, float* __restrict__ psum_part) {
  __shared__ float l_ps[NEXP];
  __shared__ int   l_cnt[NEXP];
  int tid = threadIdx.x, wv = tid >> 6, lane = tid & 63;
  if (tid < NEXP) { l_ps[tid] = 0.f; l_cnt[tid] = 0; }
  __syncthreads();

  int t = blockIdx.x * 4 + wv;
  const float4* xr = (const float4*)(x + (size_t)t * D_MODEL);
  float acc[NEXP];
#pragma unroll
  for (int e = 0; e < NEXP; ++e) acc[e] = 0.f;
#pragma unroll
  for (int i = 0; i < 4; ++i) {
    int c4 = lane + 64 * i;
    float4 v = xr[c4];
    const float* wr = Wg + c4 * 4 * NEXP;
#pragma unroll
    for (int j = 0; j < 4; ++j) {
      float xv = (&v.x)[j];
#pragma unroll
      for (int e = 0; e < NEXP; ++e) acc[e] += xv * wr[j * NEXP + e];
    }
  }
#pragma unroll
  for (int off = 32; off; off >>= 1)
#pragma unroll
    for (int e = 0; e < NEXP; ++e) acc[e] += __shfl_down(acc[e], off);

  if (lane == 0) {
    float m = acc[0];
#pragma unroll
    for (int e = 1; e < NEXP; ++e) m = fmaxf(m, acc[e]);
    float p[NEXP], s = 0.f;
#pragma unroll
    for (int e = 0; e < NEXP; ++e) { p[e] = expf(acc[e] - m); s += p[e]; }
    float inv = 1.f / s;
#pragma unroll
    for (int e = 0; e < NEXP; ++e) p[e] *= inv;
    int i0 = 0; float v0 = p[0];
#pragma unroll
    for (int e = 1; e < NEXP; ++e) if (p[e] > v0) { v0 = p[e]; i0 = e; }
    int i1 = -1; float v1 = -1.f;
#pragma unroll
    for (int e = 0; e < NEXP; ++e) if (e != i0 && p[e] > v1) { v1 = p[e]; i1 = e; }
    float denom = 1.f / (v0 + v1 + 1e-9f);
    assign_e[2 * t] = i0;     assign_w[2 * t] = v0 * denom;
    assign_e[2 * t + 1] = i1; assign_w[2 * t + 1] = v1 * denom;
    atomicAdd(&l_cnt[i0], 1);
    atomicAdd(&l_cnt[i1], 1);
#pragma unroll
    for (int e = 0; e < NEXP; ++e) atomicAdd(&l_ps[e], p[e]);
  }
  __syncthreads();
  if (tid < NEXP) {
    psum_part[blockIdx.x * NEXP + tid] = l_ps[tid];
    cnt_part[blockIdx.x * NEXP + tid] = l_cnt[tid];
  }
}

// ---------------- scan: reduce partials -> cnt/offs + aux loss ----------------
__global__ __launch_bounds__(256) void scan_kernel(const int* __restrict__ cnt_part, const float* __restrict__ psum_part,
                                                   int* __restrict__ cnt, int* __restrict__ offs,
                                                   float* __restrict__ aux_out) {
  __shared__ float sp[256];
  __shared__ int   sc[256];
  int tid = threadIdx.x;
  int e = tid & 7, c = tid >> 3;
  float fs = 0.f; int is = 0;
  for (int b = c; b < NGBLK; b += 32) {
    fs += psum_part[b * NEXP + e];
    is += cnt_part[b * NEXP + e];
  }
  sp[tid] = fs; sc[tid] = is;
  __syncthreads();
  if (tid < NEXP) {
    float f = 0.f; int n = 0;
    for (int c2 = 0; c2 < 32; ++c2) { f += sp[c2 * 8 + tid]; n += sc[c2 * 8 + tid]; }
    cnt[tid] = n; sp[tid] = f;
  }
  __syncthreads();
  if (tid == 0) {
    int o = 0; float aux = 0.f;
    for (int e2 = 0; e2 < NEXP; ++e2) {
      offs[e2] = o; o += cnt[e2];
      aux += (float)cnt[e2] * sp[e2];
    }
    aux_out[0] = aux * (float)NEXP / ((float)NTOK * (float)NTOK);
  }
}

// ---------------- scatter: compact assignments per expert ----------------
__global__ __launch_bounds__(256) void scatter_kernel(const int* __restrict__ assign_e,
                                                      const int* __restrict__ offs, int* __restrict__ cursor,
                                                      int* __restrict__ slot_tok, int* __restrict__ slot_of) {
  __shared__ int lhist[NEXP], lbase[NEXP];
  int tid = threadIdx.x;
  int a = blockIdx.x * 256 + tid;
  if (tid < NEXP) lhist[tid] = 0;
  __syncthreads();
  int e = assign_e[a];
  int lp = atomicAdd(&lhist[e], 1);
  __syncthreads();
  if (tid < NEXP) lbase[tid] = atomicAdd(&cursor[tid], lhist[tid]);
  __syncthreads();
  int s = offs[e] + lbase[e] + lp;
  slot_tok[s] = a >> 1;
  slot_of[a] = s;
}

// ================= 8-phase 256x256 GEMM, BK=32, 4 LDS buffers, counted vmcnt =================
// EPI 0: H = gelu(gather(xb) @ W1 + b1) -> bf16 ; EPI 1: y = H @ W2 + b2 -> fp32
// LDS buffer b (32KB): A tile [256][32] shorts at b*16384, B tile [256][32] at +8192 shorts.
// Swizzle: element (row, chunk c) lives at slot c ^ ((row>>1)&3); source is pre-swizzled,
// LDS dest linear (rule 21). Read-side XOR collapses to lane constant (l>>4)^((l>>1)&3).
template<int KD, int ND, int EPI>
__global__ __launch_bounds__(512, 2) void gemm8p(
    const short* __restrict__ Asrc, const short* __restrict__ Bsrc,
    const float* __restrict__ bias, const int* __restrict__ slot_tok,
    const int* __restrict__ cnt, const int* __restrict__ offs,
    void* __restrict__ OutP)
{
  constexpr int NT = KD / 32;
  extern __shared__ __align__(16) short lds[];
  int e = blockIdx.z;
  int cn = cnt[e];
  int rt = blockIdx.y;
  if (rt * 256 >= cn) return;
  int ft = blockIdx.x;
  int off = offs[e];
  int tid = threadIdx.x;
  int l = tid & 63, w = tid >> 6;
  int wm = w >> 2, wn = w & 3;
  int l15 = l & 15;

  // ---- staging source pointers (pre-swizzled k-slot) ----
  int srow = tid >> 2;
  int sw8 = ((tid & 3) ^ ((tid >> 3) & 3)) * 8;
  int g0 = rt * 256 + srow, g1 = g0 + 128;
  int i0 = g0 < cn ? g0 : cn - 1;
  int i1 = g1 < cn ? g1 : cn - 1;
  const short *a0, *a1;
  if (EPI == 0) {
    a0 = Asrc + (size_t)slot_tok[off + i0] * KD + sw8;
    a1 = Asrc + (size_t)slot_tok[off + i1] * KD + sw8;
  } else {
    a0 = Asrc + (size_t)(off + i0) * KD + sw8;
    a1 = Asrc + (size_t)(off + i1) * KD + sw8;
  }
  const short* be = Bsrc + (size_t)e * ND * KD + (size_t)(ft * 256) * KD + sw8;
  const short* b0 = be + (size_t)srow * KD;
  const short* b1 = be + (size_t)(srow + 128) * KD;
  short* dA = lds + tid * 8;           // linear dest, bytes tid*16
  short* dB = lds + 8192 + tid * 8;

  // ---- prologue: stage tiles 0..2 (12 loads/thread) ----
#pragma unroll
  for (int p = 0; p < 3; ++p) {
    short* bA = dA + p * 16384;
    short* bB = dB + p * 16384;
    gload_lds16(a0, bA); gload_lds16(a1, bA + 4096);
    gload_lds16(b0, bB); gload_lds16(b1, bB + 4096);
    a0 += 32; a1 += 32; b0 += 32; b1 += 32;
  }
  asm volatile("s_waitcnt vmcnt(8)" ::: "memory");   // tile 0 landed
  __builtin_amdgcn_s_barrier();

  // ---- fragment read bases (swizzled) ----
  int cs8 = (((l >> 4) ^ ((l >> 1) & 3))) * 8;
  const short* Afr = lds + (wm * 128 + l15) * 32 + cs8;
  const short* Bfr = lds + 8192 + (wn * 64 + l15) * 32 + cs8;

  f32x4 acc[8][4] = {};

  for (int t = 0; t < NT; ++t) {
    int bb = (t & 3) * 16384;
    bool stg = (t + 3 < NT);
    int sb = ((t + 3) & 3) * 16384;
    short8 af[4], bq[4];
    // ---- phase 0: read B n0-3 + A m0-3, stage A(t+3), 16 MFMA ----
#pragma unroll
    for (int n = 0; n < 4; ++n) bq[n] = *(const short8*)(Bfr + bb + n * 512);
#pragma unroll
    for (int m = 0; m < 4; ++m) af[m] = *(const short8*)(Afr + bb + m * 512);
    if (stg) { gload_lds16(a0, dA + sb); gload_lds16(a1, dA + sb + 4096); }
    __builtin_amdgcn_s_barrier();
    __builtin_amdgcn_s_setprio(1);
#pragma unroll
    for (int m = 0; m < 4; ++m)
#pragma unroll
      for (int n = 0; n < 4; ++n)
        acc[m][n] = __builtin_amdgcn_mfma_f32_16x16x32_bf16(af[m], bq[n], acc[m][n], 0, 0, 0);
    __builtin_amdgcn_s_setprio(0);
    __builtin_amdgcn_s_barrier();
    // ---- phase 1: read A m4-7, stage B(t+3), 16 MFMA ----
#pragma unroll
    for (int m = 0; m < 4; ++m) af[m] = *(const short8*)(Afr + bb + (m + 4) * 512);
    if (stg) {
      gload_lds16(b0, dB + sb); gload_lds16(b1, dB + sb + 4096);
      a0 += 32; a1 += 32; b0 += 32; b1 += 32;
    }
    __builtin_amdgcn_s_barrier();
    __builtin_amdgcn_s_setprio(1);
#pragma unroll
    for (int m = 0; m < 4; ++m)
#pragma unroll
      for (int n = 0; n < 4; ++n)
        acc[m + 4][n] = __builtin_amdgcn_mfma_f32_16x16x32_bf16(af[m], bq[n], acc[m + 4][n], 0, 0, 0);
    __builtin_amdgcn_s_setprio(0);
    // ---- tile-end counted wait: next tile landed; never 0 until tail ----
    if (t < NT - 3)       { asm volatile("s_waitcnt vmcnt(8)" ::: "memory"); }
    else if (t == NT - 3) { asm volatile("s_waitcnt vmcnt(4)" ::: "memory"); }
    else if (t == NT - 2) { asm volatile("s_waitcnt vmcnt(0)" ::: "memory"); }
    __builtin_amdgcn_s_barrier();
  }

  // ---- epilogue ----
  int colb = ft * 256 + wn * 64 + l15;
  float bv[4];
#pragma unroll
  for (int n = 0; n < 4; ++n) bv[n] = bias[e * ND + colb + n * 16];
  int r0 = rt * 256 + wm * 128 + ((l >> 4) << 2);
  if (EPI == 0) {
    short* H = (short*)OutP;
#pragma unroll
    for (int m = 0; m < 8; ++m)
#pragma unroll
      for (int n = 0; n < 4; ++n)
#pragma unroll
        for (int j = 0; j < 4; ++j) {
          int grow = r0 + m * 16 + j;
          if (grow < cn) {
            float v = gelu_f(acc[m][n][j] + bv[n]);
            H[(size_t)(off + grow) * ND + colb + n * 16] = f2bf(v);
          }
        }
  } else {
    float* Y = (float*)OutP;
#pragma unroll
    for (int m = 0; m < 8; ++m)
#pragma unroll
      for (int n = 0; n < 4; ++n)
#pragma unroll
        for (int j = 0; j < 4; ++j) {
          int grow = r0 + m * 16 + j;
          if (grow < cn)
            Y[(size_t)(off + grow) * ND + colb + n * 16] = acc[m][n][j] + bv[n];
        }
  }
}

// ---------------- combine: out[t] = w0*y[s0] + w1*y[s1] ----------------
__global__ __launch_bounds__(256) void combine_kernel(const float* __restrict__ y, const int* __restrict__ slot_of,
                                                      const float* __restrict__ assign_w, float* __restrict__ out) {
  int t = blockIdx.x;
  int d4 = threadIdx.x;
  int s0 = slot_of[2 * t], s1 = slot_of[2 * t + 1];
  float w0 = assign_w[2 * t], w1 = assign_w[2 * t + 1];
  float4 a = ((const float4*)(y + (size_t)s0 * D_MODEL))[d4];
  float4 b = ((const float4*)(y + (size_t)s1 * D_MODEL))[d4];
  float4 o;
  o.x = w0 * a.x + w1 * b.x;
  o.y = w0 * a.y + w1 * b.y;
  o.z = w0 * a.z + w1 * b.z;
  o.w = w0 * a.w + w1 * b.w;
  ((float4*)(out + (size_t)t * D_MODEL))[d4] = o;
}

extern "C" void kernel_launch(void* const* d_in, const int* in_sizes, int n_in,
                              void* d_out, int out_size, void* d_ws, size_t ws_size,
                              hipStream_t stream) {
  const float* x  = (const float*)d_in[0];
  const float* Wg = (const float*)d_in[1];
  const float* W1 = (const float*)d_in[2];
  const float* b1 = (const float*)d_in[3];
  const float* W2 = (const float*)d_in[4];
  const float* b2 = (const float*)d_in[5];
  float* out = (float*)d_out;
  char* ws = (char*)d_ws;

  // workspace layout (~285.6 MB)
  short* xb       = (short*)(ws);                       // 16,777,216 B
  short* w1t      = (short*)(ws + 16777216);            // 67,108,864 B  [e][f][k] bf16
  float* y        = (float*)(ws + 16777216);            // aliases w1t (dead after gemm1): 16384x1024 fp32
  short* w2t      = (short*)(ws + 83886080);            // 67,108,864 B  [e][d][ff] bf16
  short* H        = (short*)(ws + 150994944);           // 134,217,728 B 16384 x 4096 bf16
  int*   slot_tok = (int*)  (ws + 285212672);
  int*   assign_e = (int*)  (ws + 285278208);
  float* assign_w = (float*)(ws + 285343744);
  int*   slot_of  = (int*)  (ws + 285409280);
  int*   cnt_part = (int*)  (ws + 285474816);
  float* psum_part= (float*)(ws + 285540352);
  int*   ctrl     = (int*)  (ws + 285605888);
  int* cnt = ctrl; int* cursor = ctrl + 8; int* offs = ctrl + 16;

  hipFuncSetAttribute(reinterpret_cast<const void*>(&gemm8p<D_MODEL, D_FF, 0>),
                      hipFuncAttributeMaxDynamicSharedMemorySize, 131072);
  hipFuncSetAttribute(reinterpret_cast<const void*>(&gemm8p<D_FF, D_MODEL, 1>),
                      hipFuncAttributeMaxDynamicSharedMemorySize, 131072);

  zero_kernel<<<1, 64, 0, stream>>>(ctrl);
  convert_x<<<8192, 256, 0, stream>>>((const float4*)x, (ushort4*)xb, NTOK * D_MODEL / 4);
  transpose_conv<<<dim3(64, 16, NEXP), 256, 0, stream>>>(W1, w1t, D_MODEL, D_FF);
  transpose_conv<<<dim3(16, 64, NEXP), 256, 0, stream>>>(W2, w2t, D_FF, D_MODEL);
  gating_kernel<<<NGBLK, 256, 0, stream>>>(x, Wg, assign_e, assign_w, cnt_part, psum_part);
  scan_kernel<<<1, 256, 0, stream>>>(cnt_part, psum_part, cnt, offs, out + (out_size - 1));
  scatter_kernel<<<NASSIGN / 256, 256, 0, stream>>>(assign_e, offs, cursor, slot_tok, slot_of);
  gemm8p<D_MODEL, D_FF, 0><<<dim3(D_FF / 256, 32, NEXP), 512, 131072, stream>>>(
      xb, w1t, b1, slot_tok, cnt, offs, H);
  gemm8p<D_FF, D_MODEL, 1><<<dim3(D_MODEL / 256, 32, NEXP), 512, 131072, stream>>>(
      H, w2t, b2, slot_tok, cnt, offs, y);
  combine_kernel<<<NTOK, 256, 0, stream>>>(y, slot_of, assign_w, out);
}

// Round 4
// 662.556 us; speedup vs baseline: 2.4308x; 1.0135x over previous
//
#include <hip/hip_runtime.h>
#include <math.h>

#define D_MODEL 1024
#define D_FF    4096
#define NEXP    8
#define NTOK    8192
#define NASSIGN (NTOK*2)
#define NGBLK   (NTOK/4)   // gating blocks (4 tokens/block)

using short8 = __attribute__((ext_vector_type(8))) short;
using short4v = __attribute__((ext_vector_type(4))) short;
using f32x4  = __attribute__((ext_vector_type(4))) float;

__device__ __forceinline__ short f2bf(float f) {
  unsigned u = __float_as_uint(f);
  unsigned r = (u + 0x7fffu + ((u >> 16) & 1u)) >> 16;
  return (short)r;
}

__device__ __forceinline__ void gload_lds16(const void* g, void* l) {
  __builtin_amdgcn_global_load_lds((const __attribute__((address_space(1))) void*)g,
                                   (__attribute__((address_space(3))) void*)l, 16, 0, 0);
}

// fast erf-gelu: Abramowitz-Stegun 7.1.26, |eps| <= 1.5e-7
__device__ __forceinline__ float gelu_f(float x) {
  float z = 0.70710678118f * x;
  float a = fabsf(z);
  float t = 1.0f / (1.0f + 0.3275911f * a);
  float p = t * (0.254829592f + t * (-0.284496736f + t * (1.421413741f +
            t * (-1.453152027f + t * 1.061405429f))));
  float er = 1.0f - p * __expf(-a * a);
  er = copysignf(er, z);
  return 0.5f * x * (1.0f + er);
}

// ---------------- zero control ----------------
__global__ void zero_kernel(int* ctrl) {
  int i = threadIdx.x;
  if (i < 24) ctrl[i] = 0;   // cnt[8], cursor[8], off[8]
}

// ---------------- x fp32 -> bf16 ----------------
__global__ __launch_bounds__(256) void convert_x(const float4* __restrict__ x, ushort4* __restrict__ xb, int n4) {
  int i = blockIdx.x * 256 + threadIdx.x;
  if (i < n4) {
    float4 v = x[i];
    ushort4 o;
    o.x = (unsigned short)f2bf(v.x);
    o.y = (unsigned short)f2bf(v.y);
    o.z = (unsigned short)f2bf(v.z);
    o.w = (unsigned short)f2bf(v.w);
    xb[i] = o;
  }
}

// ---------------- transpose + convert: in[e][R][C] fp32 -> out[e][C][R] bf16 ----------------
__global__ __launch_bounds__(256) void transpose_conv(const float* __restrict__ in, short* __restrict__ out,
                                                      int R, int C) {
  __shared__ float t[64][65];
  int e = blockIdx.z;
  size_t base = (size_t)e * R * C;
  int r0 = blockIdx.y * 64, c0 = blockIdx.x * 64;
  int lr = threadIdx.x >> 6, lc = threadIdx.x & 63;
#pragma unroll
  for (int j = 0; j < 16; ++j) {
    int rr = lr + j * 4;
    t[rr][lc] = in[base + (size_t)(r0 + rr) * C + c0 + lc];
  }
  __syncthreads();
#pragma unroll
  for (int j = 0; j < 16; ++j) {
    int oc = lr + j * 4;
    out[base + (size_t)(c0 + oc) * R + r0 + lc] = f2bf(t[lc][oc]);
  }
}

// ---------------- gating: one wave per token, block-local reduction ----------------
__global__ __launch_bounds__(256) void gating_kernel(const float* __restrict__ x, const float* __restrict__ Wg,
                                                     int* __restrict__ assign_e, float* __restrict__ assign_w,
                                                     int* __restrict__ cnt_part, float* __restrict__ psum_part) {
  __shared__ float l_ps[NEXP];
  __shared__ int   l_cnt[NEXP];
  int tid = threadIdx.x, wv = tid >> 6, lane = tid & 63;
  if (tid < NEXP) { l_ps[tid] = 0.f; l_cnt[tid] = 0; }
  __syncthreads();

  int t = blockIdx.x * 4 + wv;
  const float4* xr = (const float4*)(x + (size_t)t * D_MODEL);
  float acc[NEXP];
#pragma unroll
  for (int e = 0; e < NEXP; ++e) acc[e] = 0.f;
#pragma unroll
  for (int i = 0; i < 4; ++i) {
    int c4 = lane + 64 * i;
    float4 v = xr[c4];
    const float* wr = Wg + c4 * 4 * NEXP;
#pragma unroll
    for (int j = 0; j < 4; ++j) {
      float xv = (&v.x)[j];
#pragma unroll
      for (int e = 0; e < NEXP; ++e) acc[e] += xv * wr[j * NEXP + e];
    }
  }
#pragma unroll
  for (int off = 32; off; off >>= 1)
#pragma unroll
    for (int e = 0; e < NEXP; ++e) acc[e] += __shfl_down(acc[e], off);

  if (lane == 0) {
    float m = acc[0];
#pragma unroll
    for (int e = 1; e < NEXP; ++e) m = fmaxf(m, acc[e]);
    float p[NEXP], s = 0.f;
#pragma unroll
    for (int e = 0; e < NEXP; ++e) { p[e] = expf(acc[e] - m); s += p[e]; }
    float inv = 1.f / s;
#pragma unroll
    for (int e = 0; e < NEXP; ++e) p[e] *= inv;
    int i0 = 0; float v0 = p[0];
#pragma unroll
    for (int e = 1; e < NEXP; ++e) if (p[e] > v0) { v0 = p[e]; i0 = e; }
    int i1 = -1; float v1 = -1.f;
#pragma unroll
    for (int e = 0; e < NEXP; ++e) if (e != i0 && p[e] > v1) { v1 = p[e]; i1 = e; }
    float denom = 1.f / (v0 + v1 + 1e-9f);
    assign_e[2 * t] = i0;     assign_w[2 * t] = v0 * denom;
    assign_e[2 * t + 1] = i1; assign_w[2 * t + 1] = v1 * denom;
    atomicAdd(&l_cnt[i0], 1);
    atomicAdd(&l_cnt[i1], 1);
#pragma unroll
    for (int e = 0; e < NEXP; ++e) atomicAdd(&l_ps[e], p[e]);
  }
  __syncthreads();
  if (tid < NEXP) {
    psum_part[blockIdx.x * NEXP + tid] = l_ps[tid];
    cnt_part[blockIdx.x * NEXP + tid] = l_cnt[tid];
  }
}

// ---------------- scan: reduce partials -> cnt/offs + aux loss ----------------
__global__ __launch_bounds__(256) void scan_kernel(const int* __restrict__ cnt_part, const float* __restrict__ psum_part,
                                                   int* __restrict__ cnt, int* __restrict__ offs,
                                                   float* __restrict__ aux_out) {
  __shared__ float sp[256];
  __shared__ int   sc[256];
  int tid = threadIdx.x;
  int e = tid & 7, c = tid >> 3;
  float fs = 0.f; int is = 0;
  for (int b = c; b < NGBLK; b += 32) {
    fs += psum_part[b * NEXP + e];
    is += cnt_part[b * NEXP + e];
  }
  sp[tid] = fs; sc[tid] = is;
  __syncthreads();
  if (tid < NEXP) {
    float f = 0.f; int n = 0;
    for (int c2 = 0; c2 < 32; ++c2) { f += sp[c2 * 8 + tid]; n += sc[c2 * 8 + tid]; }
    cnt[tid] = n; sp[tid] = f;
  }
  __syncthreads();
  if (tid == 0) {
    int o = 0; float aux = 0.f;
    for (int e2 = 0; e2 < NEXP; ++e2) {
      offs[e2] = o; o += cnt[e2];
      aux += (float)cnt[e2] * sp[e2];
    }
    aux_out[0] = aux * (float)NEXP / ((float)NTOK * (float)NTOK);
  }
}

// ---------------- scatter: compact assignments per expert ----------------
__global__ __launch_bounds__(256) void scatter_kernel(const int* __restrict__ assign_e,
                                                      const int* __restrict__ offs, int* __restrict__ cursor,
                                                      int* __restrict__ slot_tok, int* __restrict__ slot_of) {
  __shared__ int lhist[NEXP], lbase[NEXP];
  int tid = threadIdx.x;
  int a = blockIdx.x * 256 + tid;
  if (tid < NEXP) lhist[tid] = 0;
  __syncthreads();
  int e = assign_e[a];
  int lp = atomicAdd(&lhist[e], 1);
  __syncthreads();
  if (tid < NEXP) lbase[tid] = atomicAdd(&cursor[tid], lhist[tid]);
  __syncthreads();
  int s = offs[e] + lbase[e] + lp;
  slot_tok[s] = a >> 1;
  slot_of[a] = s;
}

// ================= 128x128 tile, BK=32, explicit double-buffer, counted 2-phase =================
// T3-minimum schedule (m248): STAGE(next) first, then ds_read+MFMA, one vmcnt(0)+barrier per tile.
// 32 KiB LDS + ~130 VGPR -> 3 blocks/CU co-resident (latency absorbed across blocks, m114).
// Transposed-C: mfma(bq, af) puts consecutive output COLUMNS in reg j -> short4/float4 stores.
// k-slot swizzle (verified 0 conflicts in R3): data chunk c lives at slot c ^ ((row>>1)&3).
template<int KD, int ND, int EPI>
__global__ __launch_bounds__(256, 3) void gemm2p(
    const short* __restrict__ Asrc, const short* __restrict__ Bsrc,
    const float* __restrict__ bias, const int* __restrict__ slot_tok,
    const int* __restrict__ cnt, const int* __restrict__ offs,
    void* __restrict__ OutP)
{
  constexpr int NT = KD / 32;
  __shared__ short As[2][4096];   // [buf][128 rows][32 k]
  __shared__ short Bs[2][4096];
  int e = blockIdx.z;
  int cn = cnt[e];
  int rt = blockIdx.y;
  if (rt * 128 >= cn) return;
  int ft = blockIdx.x;
  int off = offs[e];
  int tid = threadIdx.x, l = tid & 63, w = tid >> 6;
  int wr = w >> 1, wf = w & 1, l15 = l & 15;

  // staging: thread covers rows (tid>>2) and (tid>>2)+64; source chunk pre-swizzled
  int srow = tid >> 2;
  int sw8 = ((tid & 3) ^ ((tid >> 3) & 3)) * 8;
  int g0 = rt * 128 + srow, g1 = g0 + 64;
  int i0 = g0 < cn ? g0 : cn - 1;
  int i1 = g1 < cn ? g1 : cn - 1;
  const short *a0, *a1;
  if (EPI == 0) {
    a0 = Asrc + (size_t)slot_tok[off + i0] * KD + sw8;
    a1 = Asrc + (size_t)slot_tok[off + i1] * KD + sw8;
  } else {
    a0 = Asrc + (size_t)(off + i0) * KD + sw8;
    a1 = Asrc + (size_t)(off + i1) * KD + sw8;
  }
  const short* bbase = Bsrc + (size_t)e * ND * KD + (size_t)(ft * 128) * KD + sw8;
  const short* b0 = bbase + (size_t)srow * KD;
  const short* b1 = bbase + (size_t)(srow + 64) * KD;

  // prologue: stage tile 0 into buf 0
  gload_lds16(a0, (char*)As[0] + tid * 16); gload_lds16(a1, (char*)As[0] + 4096 + tid * 16);
  gload_lds16(b0, (char*)Bs[0] + tid * 16); gload_lds16(b1, (char*)Bs[0] + 4096 + tid * 16);
  a0 += 32; a1 += 32; b0 += 32; b1 += 32;
  asm volatile("s_waitcnt vmcnt(0)" ::: "memory");
  __syncthreads();

  int cs8 = ((l >> 4) ^ ((l >> 1) & 3)) * 8;   // read slot = wanted k-group XOR row-swizzle
  const short* Ard = &As[0][(wr * 64 + l15) * 32] + cs8;
  const short* Brd = &Bs[0][(wf * 64 + l15) * 32] + cs8;
  f32x4 acc[4][4] = {};

  for (int t = 0; t < NT; ++t) {
    int cur = t & 1;
    if (t + 1 < NT) {   // stage next tile FIRST (latency hides under reads+MFMA)
      char* dA = (char*)As[cur ^ 1] + tid * 16;
      char* dB = (char*)Bs[cur ^ 1] + tid * 16;
      gload_lds16(a0, dA); gload_lds16(a1, dA + 4096);
      gload_lds16(b0, dB); gload_lds16(b1, dB + 4096);
      a0 += 32; a1 += 32; b0 += 32; b1 += 32;
    }
    const short* Ac = Ard + cur * 4096;
    const short* Bc = Brd + cur * 4096;
    short8 af[4], bq[4];
#pragma unroll
    for (int m = 0; m < 4; ++m) af[m] = *(const short8*)(Ac + m * 512);
#pragma unroll
    for (int n = 0; n < 4; ++n) bq[n] = *(const short8*)(Bc + n * 512);
    __builtin_amdgcn_s_setprio(1);
#pragma unroll
    for (int m = 0; m < 4; ++m)
#pragma unroll
      for (int n = 0; n < 4; ++n)   // transposed-C: D rows = f/d cols, D cols = tokens
        acc[m][n] = __builtin_amdgcn_mfma_f32_16x16x32_bf16(bq[n], af[m], acc[m][n], 0, 0, 0);
    __builtin_amdgcn_s_setprio(0);
    asm volatile("s_waitcnt vmcnt(0)" ::: "memory");
    __syncthreads();
  }

  // epilogue: acc[m][n][j] = out[tok = rt*128+wr*64+m*16+l15][col = ft*128+wf*64+n*16+(l>>4)*4+j]
  int l4 = (l >> 4) << 2;
#pragma unroll
  for (int n = 0; n < 4; ++n) {
    int col = ft * 128 + wf * 64 + n * 16 + l4;
    f32x4 b4 = *(const f32x4*)&bias[e * ND + col];
#pragma unroll
    for (int m = 0; m < 4; ++m) {
      int tok = rt * 128 + wr * 64 + m * 16 + l15;
      if (tok < cn) {
        if (EPI == 0) {
          short4v h;
#pragma unroll
          for (int j = 0; j < 4; ++j) h[j] = f2bf(gelu_f(acc[m][n][j] + b4[j]));
          *(short4v*)((short*)OutP + (size_t)(off + tok) * ND + col) = h;
        } else {
          f32x4 o;
#pragma unroll
          for (int j = 0; j < 4; ++j) o[j] = acc[m][n][j] + b4[j];
          *(f32x4*)((float*)OutP + (size_t)(off + tok) * ND + col) = o;
        }
      }
    }
  }
}

// ---------------- combine: out[t] = w0*y[s0] + w1*y[s1] ----------------
__global__ __launch_bounds__(256) void combine_kernel(const float* __restrict__ y, const int* __restrict__ slot_of,
                                                      const float* __restrict__ assign_w, float* __restrict__ out) {
  int t = blockIdx.x;
  int d4 = threadIdx.x;
  int s0 = slot_of[2 * t], s1 = slot_of[2 * t + 1];
  float w0 = assign_w[2 * t], w1 = assign_w[2 * t + 1];
  float4 a = ((const float4*)(y + (size_t)s0 * D_MODEL))[d4];
  float4 b = ((const float4*)(y + (size_t)s1 * D_MODEL))[d4];
  float4 o;
  o.x = w0 * a.x + w1 * b.x;
  o.y = w0 * a.y + w1 * b.y;
  o.z = w0 * a.z + w1 * b.z;
  o.w = w0 * a.w + w1 * b.w;
  ((float4*)(out + (size_t)t * D_MODEL))[d4] = o;
}

extern "C" void kernel_launch(void* const* d_in, const int* in_sizes, int n_in,
                              void* d_out, int out_size, void* d_ws, size_t ws_size,
                              hipStream_t stream) {
  const float* x  = (const float*)d_in[0];
  const float* Wg = (const float*)d_in[1];
  const float* W1 = (const float*)d_in[2];
  const float* b1 = (const float*)d_in[3];
  const float* W2 = (const float*)d_in[4];
  const float* b2 = (const float*)d_in[5];
  float* out = (float*)d_out;
  char* ws = (char*)d_ws;

  // workspace layout (~285.6 MB)
  short* xb       = (short*)(ws);                       // 16,777,216 B
  short* w1t      = (short*)(ws + 16777216);            // 67,108,864 B  [e][f][k] bf16
  float* y        = (float*)(ws + 16777216);            // aliases w1t (dead after gemm1): 16384x1024 fp32
  short* w2t      = (short*)(ws + 83886080);            // 67,108,864 B  [e][d][ff] bf16
  short* H        = (short*)(ws + 150994944);           // 134,217,728 B 16384 x 4096 bf16
  int*   slot_tok = (int*)  (ws + 285212672);
  int*   assign_e = (int*)  (ws + 285278208);
  float* assign_w = (float*)(ws + 285343744);
  int*   slot_of  = (int*)  (ws + 285409280);
  int*   cnt_part = (int*)  (ws + 285474816);
  float* psum_part= (float*)(ws + 285540352);
  int*   ctrl     = (int*)  (ws + 285605888);
  int* cnt = ctrl; int* cursor = ctrl + 8; int* offs = ctrl + 16;

  zero_kernel<<<1, 64, 0, stream>>>(ctrl);
  convert_x<<<8192, 256, 0, stream>>>((const float4*)x, (ushort4*)xb, NTOK * D_MODEL / 4);
  transpose_conv<<<dim3(64, 16, NEXP), 256, 0, stream>>>(W1, w1t, D_MODEL, D_FF);
  transpose_conv<<<dim3(16, 64, NEXP), 256, 0, stream>>>(W2, w2t, D_FF, D_MODEL);
  gating_kernel<<<NGBLK, 256, 0, stream>>>(x, Wg, assign_e, assign_w, cnt_part, psum_part);
  scan_kernel<<<1, 256, 0, stream>>>(cnt_part, psum_part, cnt, offs, out + (out_size - 1));
  scatter_kernel<<<NASSIGN / 256, 256, 0, stream>>>(assign_e, offs, cursor, slot_tok, slot_of);
  gemm2p<D_MODEL, D_FF, 0><<<dim3(D_FF / 128, 64, NEXP), 256, 0, stream>>>(
      xb, w1t, b1, slot_tok, cnt, offs, H);
  gemm2p<D_FF, D_MODEL, 1><<<dim3(D_MODEL / 128, 64, NEXP), 256, 0, stream>>>(
      H, w2t, b2, slot_tok, cnt, offs, y);
  combine_kernel<<<NTOK, 256, 0, stream>>>(y, slot_of, assign_w, out);
}